// Round 5
// baseline (550.741 us; speedup 1.0000x reference)
//
#include <hip/hip_runtime.h>
#include <math.h>

#define NVIEW 4
#define BATCH 4
#define NSEQ  256
#define CDIM  768
#define HEADS 12
#define HD    64

typedef __attribute__((ext_vector_type(8))) short   short8;
typedef __attribute__((ext_vector_type(8))) unsigned short ushort8;
typedef __attribute__((ext_vector_type(4))) float   float4v;

typedef const __attribute__((address_space(1))) void gas_t;
typedef       __attribute__((address_space(3))) void las_t;

__device__ __forceinline__ unsigned short f2b(float x)
{
    union { float f; unsigned u; } c; c.f = x;
    unsigned r = (c.u + 0x7FFFu + ((c.u >> 16) & 1u)) >> 16;
    return (unsigned short)r;
}

// ---------------------------------------------------------------------------
// f32 -> bf16 conversion (n must be multiple of 8)
// ---------------------------------------------------------------------------
__global__ void conv_bf16(const float* __restrict__ src, unsigned short* __restrict__ dst, int n)
{
    int idx = (blockIdx.x * 256 + threadIdx.x) * 8;
    if (idx >= n) return;
    float4 a = *(const float4*)(src + idx);
    float4 b = *(const float4*)(src + idx + 4);
    ushort8 o;
    o[0] = f2b(a.x); o[1] = f2b(a.y); o[2] = f2b(a.z); o[3] = f2b(a.w);
    o[4] = f2b(b.x); o[5] = f2b(b.y); o[6] = f2b(b.z); o[7] = f2b(b.w);
    *(ushort8*)(dst + idx) = o;
}

// x2 = xbuf + fc2_b[v, c]  -> bf16   (3,145,728 elements, 8/thread)
__global__ void conv_bias_bf16(const float* __restrict__ src, const float* __restrict__ bias,
                               unsigned short* __restrict__ dst)
{
    int gid = blockIdx.x * 256 + threadIdx.x;
    long i8 = (long)gid * 8;
    int v = (int)(i8 / 786432);
    int c = (int)(i8 % 768);
    const float* bb = bias + v * 768 + c;
    float4 a = *(const float4*)(src + i8);
    float4 b = *(const float4*)(src + i8 + 4);
    ushort8 o;
    o[0] = f2b(a.x + bb[0]); o[1] = f2b(a.y + bb[1]);
    o[2] = f2b(a.z + bb[2]); o[3] = f2b(a.w + bb[3]);
    o[4] = f2b(b.x + bb[4]); o[5] = f2b(b.y + bb[5]);
    o[6] = f2b(b.z + bb[6]); o[7] = f2b(b.w + bb[7]);
    *(ushort8*)(dst + i8) = o;
}

// xbuf[v,row,c] = 2*proj_b[v,c]   (786,432 float4 stores / 4)
__global__ void init2b(const float* __restrict__ pb, float* __restrict__ xb)
{
    int gid = blockIdx.x * 256 + threadIdx.x;
    long i4 = (long)gid * 4;
    int v = (int)(i4 / 786432);
    int c = (int)(i4 % 768);
    const float* s = pb + v * 768 + c;
    *(float4*)(xb + i4) = make_float4(2.f * s[0], 2.f * s[1], 2.f * s[2], 2.f * s[3]);
}

// KVH[v,row,c] = mha_in_b[v*2304 + 768 + c], c in [0,1536)
__global__ void init_kvh(const float* __restrict__ bin, float* __restrict__ kvh)
{
    int gid = blockIdx.x * 256 + threadIdx.x;
    long i4 = (long)gid * 4;
    int v = (int)(i4 / 1572864);
    int c = (int)(i4 % 1536);
    const float* s = bin + v * 2304 + 768 + c;
    *(float4*)(kvh + i4) = make_float4(s[0], s[1], s[2], s[3]);
}

// ---------------------------------------------------------------------------
// LayerNorm -> bf16 out
// ---------------------------------------------------------------------------
__device__ __forceinline__ void block_ln_row_b(const float* __restrict__ xrow,
                                               const float* __restrict__ g,
                                               const float* __restrict__ b,
                                               unsigned short* __restrict__ orow)
{
    const int t = threadIdx.x;
    float x0 = xrow[t], x1 = xrow[t + 256], x2 = xrow[t + 512];
    float s  = x0 + x1 + x2;
    float s2 = x0 * x0 + x1 * x1 + x2 * x2;
    #pragma unroll
    for (int off = 32; off > 0; off >>= 1) {
        s  += __shfl_down(s, off);
        s2 += __shfl_down(s2, off);
    }
    __shared__ float w1[4], w2[4];
    if ((t & 63) == 0) { w1[t >> 6] = s; w2[t >> 6] = s2; }
    __syncthreads();
    float S  = w1[0] + w1[1] + w1[2] + w1[3];
    float S2 = w2[0] + w2[1] + w2[2] + w2[3];
    float mean = S * (1.0f / 768.0f);
    float var  = S2 * (1.0f / 768.0f) - mean * mean;
    float inv  = rsqrtf(var + 1e-6f);
    orow[t]       = f2b((x0 - mean) * inv * g[t]       + b[t]);
    orow[t + 256] = f2b((x1 - mean) * inv * g[t + 256] + b[t + 256]);
    orow[t + 512] = f2b((x2 - mean) * inv * g[t + 512] + b[t + 512]);
}

// X:[B,V,N,C] -> Xn bf16 [V,B,N,C]
__global__ void ln1_kernel(const float* __restrict__ X, const float* __restrict__ g,
                           const float* __restrict__ b, unsigned short* __restrict__ Xn)
{
    int rid = blockIdx.x;
    int n  = rid & 255;
    int bv = rid >> 8;
    int bb = bv >> 2, v = bv & 3;
    const float* xrow = X + (long)rid * CDIM;
    unsigned short* orow = Xn + ((long)(v * 4 + bb) * 256 + n) * CDIM;
    block_ln_row_b(xrow, g, b, orow);
}

// f32 in [V,B,N,C] -> bf16 out, per-view gamma/beta
__global__ void ln2_kernel(const float* __restrict__ Xin, const float* __restrict__ g,
                           const float* __restrict__ b, unsigned short* __restrict__ Out)
{
    int rid = blockIdx.x;
    int v = rid >> 10;
    const float* xrow = Xin + (long)rid * CDIM;
    block_ln_row_b(xrow, g + v * CDIM, b + v * CDIM, Out + (long)rid * CDIM);
}

// ---------------------------------------------------------------------------
// bf16 MFMA grouped GEMM with optional split-K:
//   out[v] = A[v](M,K) * W[v]^T(N,K) + epilogue
// blockIdx.z = v*KSPLIT + ks; each ks does K/KSPLIT.
// EPI: 0=store bf16   1=+bias store f32   2=+bias,gelu store bf16
//      5=atomicAdd(2*acc) f32   6=atomicAdd(acc) f32
// ---------------------------------------------------------------------------
template <int EPI, int KSPLIT, typename OT>
__launch_bounds__(256, 2)
__global__ void gemm_bf16(const unsigned short* __restrict__ A,
                          const unsigned short* __restrict__ W,
                          const float* __restrict__ bias,
                          OT* __restrict__ out, int M, int N, int K,
                          long wStride, long wOff, int bStride, int bOff)
{
    const int v  = blockIdx.z / KSPLIT;
    const int ks = blockIdx.z % KSPLIT;
    const int kBeg = ks * (K / KSPLIT);
    const int kEnd = kBeg + K / KSPLIT;
    const unsigned short* Av = A + (long)v * M * K;
    const unsigned short* Wv = W + v * wStride + wOff;

    __shared__ unsigned short As[128 * 32];
    __shared__ unsigned short Bs[128 * 32];

    const int tid  = threadIdx.x;
    const int lane = tid & 63;
    const int wave = tid >> 6;
    const int l15  = lane & 15;
    const int quad = lane >> 4;
    const int row0 = blockIdx.y * 128, col0 = blockIdx.x * 128;
    const int mw = (wave & 1) * 64, nw = (wave >> 1) * 64;

    float4v acc[4][4];
    #pragma unroll
    for (int i = 0; i < 4; ++i)
        #pragma unroll
        for (int j = 0; j < 4; ++j)
            acc[i][j] = (float4v){0.f, 0.f, 0.f, 0.f};

    const int rA = wave * 32 + (lane >> 2);
    const int pA = lane & 3;

    for (int k0 = kBeg; k0 < kEnd; k0 += 32) {
        __syncthreads();
        #pragma unroll
        for (int g = 0; g < 2; ++g) {
            int r = rA + g * 16;
            int c = (pA - ((r >> 1) & 3)) & 3;
            const unsigned short* sa = Av + (long)(row0 + r) * K + k0 + c * 8;
            const unsigned short* sw = Wv + (long)(col0 + r) * K + k0 + c * 8;
            __builtin_amdgcn_global_load_lds((gas_t*)sa, (las_t*)&As[(wave * 32 + g * 16) * 32], 16, 0, 0);
            __builtin_amdgcn_global_load_lds((gas_t*)sw, (las_t*)&Bs[(wave * 32 + g * 16) * 32], 16, 0, 0);
        }
        __syncthreads();

        short8 af[4], bfr[4];
        #pragma unroll
        for (int mi = 0; mi < 4; ++mi) {
            int m = mw + mi * 16 + l15;
            int p = (quad + ((m >> 1) & 3)) & 3;
            af[mi] = *(const short8*)&As[m * 32 + p * 8];
        }
        #pragma unroll
        for (int ni = 0; ni < 4; ++ni) {
            int n = nw + ni * 16 + l15;
            int p = (quad + ((n >> 1) & 3)) & 3;
            bfr[ni] = *(const short8*)&Bs[n * 32 + p * 8];
        }
        #pragma unroll
        for (int mi = 0; mi < 4; ++mi)
            #pragma unroll
            for (int ni = 0; ni < 4; ++ni)
                acc[mi][ni] = __builtin_amdgcn_mfma_f32_16x16x32_bf16(af[mi], bfr[ni], acc[mi][ni], 0, 0, 0);
    }

    #pragma unroll
    for (int mi = 0; mi < 4; ++mi) {
        #pragma unroll
        for (int ni = 0; ni < 4; ++ni) {
            int rowb = row0 + mw + mi * 16 + quad * 4;
            int col  = col0 + nw + ni * 16 + l15;
            float bval = 0.f;
            if (EPI == 1 || EPI == 2) bval = bias[v * bStride + bOff + col];
            #pragma unroll
            for (int r = 0; r < 4; ++r) {
                float x = acc[mi][ni][r];
                long off = (long)v * M * N + (long)(rowb + r) * N + col;
                if constexpr (EPI == 0) {
                    ((unsigned short*)out)[off] = f2b(x);
                } else if constexpr (EPI == 1) {
                    ((float*)out)[off] = x + bval;
                } else if constexpr (EPI == 2) {
                    x += bval;
                    x = 0.5f * x * (1.0f + erff(x * 0.70710678118654752f));
                    ((unsigned short*)out)[off] = f2b(x);
                } else if constexpr (EPI == 5) {
                    unsafeAtomicAdd((float*)out + off, 2.0f * x);
                } else if constexpr (EPI == 6) {
                    unsafeAtomicAdd((float*)out + off, x);
                }
            }
        }
    }
}

// ---------------------------------------------------------------------------
// Fused MFMA fusion-attention.
// grid (qt=4, b*h=48, i=4); block 256 = 4 waves; each wave owns 16 query rows.
// ---------------------------------------------------------------------------
__launch_bounds__(256, 2)
__global__ void fusion_attn_mfma(const unsigned short* __restrict__ QKV,
                                 unsigned short* __restrict__ ctx)
{
    const int qt = blockIdx.x;
    const int b  = blockIdx.y / HEADS;
    const int h  = blockIdx.y % HEADS;
    const int i  = blockIdx.z;
    const int tid  = threadIdx.x;
    const int lane = tid & 63;
    const int wave = tid >> 6;
    const int l15  = lane & 15;
    const int quad = lane >> 4;

    __shared__ unsigned short Qs[64 * 72];
    __shared__ unsigned short Ks[128 * 64];
    __shared__ unsigned short Ps[64 * 136];
    __shared__ unsigned short Vt[64 * 136];

    {
        int r = tid >> 2, p16 = (tid & 3) * 16;
        const unsigned short* src = QKV + ((long)((i * 4 + b) * 256 + qt * 64 + r)) * 2304 + h * 64 + p16;
        *(ushort8*)(&Qs[r * 72 + p16])     = *(const ushort8*)(src);
        *(ushort8*)(&Qs[r * 72 + p16 + 8]) = *(const ushort8*)(src + 8);
    }

    float4v acc_o[4];
    #pragma unroll
    for (int e = 0; e < 4; ++e) acc_o[e] = (float4v){0.f, 0.f, 0.f, 0.f};

    for (int j = 0; j < 4; ++j) {
        const unsigned short* Kb = QKV + ((long)((j * 4 + b) * 256)) * 2304 + 768 + h * 64;
        const unsigned short* Vb = Kb + 768;

        float4v sacc[16];
        #pragma unroll
        for (int t = 0; t < 16; ++t) sacc[t] = (float4v){0.f, 0.f, 0.f, 0.f};

        for (int half = 0; half < 2; ++half) {
            __syncthreads();
            #pragma unroll
            for (int g = 0; g < 4; ++g) {
                int R = wave * 32 + g * 8;
                int r = R + (lane >> 3);
                int p = lane & 7;
                int c = (p - (r & 7)) & 7;
                const unsigned short* src = Kb + (long)(half * 128 + r) * 2304 + c * 8;
                __builtin_amdgcn_global_load_lds((gas_t*)src, (las_t*)&Ks[R * 64], 16, 0, 0);
            }
            __syncthreads();
            #pragma unroll
            for (int ks = 0; ks < 2; ++ks) {
                int lcq = ks * 4 + quad;
                short8 qf = *(const short8*)&Qs[(wave * 16 + l15) * 72 + lcq * 8];
                #pragma unroll
                for (int nn = 0; nn < 8; ++nn) {
                    int n = nn * 16 + l15;
                    int p = (lcq + (n & 7)) & 7;
                    short8 kf = *(const short8*)&Ks[n * 64 + p * 8];
                    sacc[half * 8 + nn] =
                        __builtin_amdgcn_mfma_f32_16x16x32_bf16(qf, kf, sacc[half * 8 + nn], 0, 0, 0);
                }
            }
        }

        float rmax[4] = {-1e30f, -1e30f, -1e30f, -1e30f};
        #pragma unroll
        for (int t = 0; t < 16; ++t)
            #pragma unroll
            for (int r = 0; r < 4; ++r)
                rmax[r] = fmaxf(rmax[r], sacc[t][r] * 0.125f);
        #pragma unroll
        for (int off = 1; off < 16; off <<= 1)
            #pragma unroll
            for (int r = 0; r < 4; ++r)
                rmax[r] = fmaxf(rmax[r], __shfl_xor(rmax[r], off));
        float rsum[4] = {0.f, 0.f, 0.f, 0.f};
        #pragma unroll
        for (int t = 0; t < 16; ++t)
            #pragma unroll
            for (int r = 0; r < 4; ++r) {
                float e = __expf(sacc[t][r] * 0.125f - rmax[r]);
                sacc[t][r] = e;
                rsum[r] += e;
            }
        #pragma unroll
        for (int off = 1; off < 16; off <<= 1)
            #pragma unroll
            for (int r = 0; r < 4; ++r)
                rsum[r] += __shfl_xor(rsum[r], off);
        float invl[4];
        #pragma unroll
        for (int r = 0; r < 4; ++r) invl[r] = 1.0f / rsum[r];

        float4v pv[4];
        #pragma unroll
        for (int e = 0; e < 4; ++e) pv[e] = (float4v){0.f, 0.f, 0.f, 0.f};

        for (int half = 0; half < 2; ++half) {
            __syncthreads();
            #pragma unroll
            for (int nn = 0; nn < 8; ++nn)
                #pragma unroll
                for (int r = 0; r < 4; ++r)
                    Ps[(wave * 16 + quad * 4 + r) * 136 + nn * 16 + l15] = f2b(sacc[half * 8 + nn][r]);
            {
                int n = tid & 127;
                int c0 = (tid >> 7) * 4;
                #pragma unroll
                for (int cc = 0; cc < 4; ++cc) {
                    int c = c0 + cc;
                    ushort8 vv = *(const ushort8*)(Vb + (long)(half * 128 + n) * 2304 + c * 8);
                    #pragma unroll
                    for (int jj = 0; jj < 8; ++jj)
                        Vt[(c * 8 + jj) * 136 + n] = vv[jj];
                }
            }
            __syncthreads();
            #pragma unroll
            for (int ks = 0; ks < 4; ++ks) {
                int lc = ks * 4 + quad;
                short8 pf = *(const short8*)&Ps[(wave * 16 + l15) * 136 + lc * 8];
                #pragma unroll
                for (int et = 0; et < 4; ++et) {
                    short8 vf = *(const short8*)&Vt[(et * 16 + l15) * 136 + lc * 8];
                    pv[et] = __builtin_amdgcn_mfma_f32_16x16x32_bf16(pf, vf, pv[et], 0, 0, 0);
                }
            }
        }
        #pragma unroll
        for (int et = 0; et < 4; ++et)
            #pragma unroll
            for (int r = 0; r < 4; ++r)
                acc_o[et][r] += pv[et][r] * invl[r];
    }

    #pragma unroll
    for (int et = 0; et < 4; ++et)
        #pragma unroll
        for (int r = 0; r < 4; ++r) {
            int row = (i * 4 + b) * 256 + qt * 64 + wave * 16 + quad * 4 + r;
            int col = h * 64 + et * 16 + l15;
            ctx[(long)row * 768 + col] = f2b(acc_o[et][r] * 0.25f);
        }
}

// ---------------------------------------------------------------------------
// qh[v,d] = query . wq[v,d,:] + bq[v,d]
// ---------------------------------------------------------------------------
__global__ void qh_kernel(const float* __restrict__ query, const float* __restrict__ Win,
                          const float* __restrict__ Bin, float* __restrict__ QH)
{
    int gid = blockIdx.x * 256 + threadIdx.x;
    int v = gid / 768, d = gid - v * 768;
    const float* w = Win + ((long)v * 2304 + d) * 768;
    float s = 0.f;
    for (int c = 0; c < 768; c += 4) {
        float4 w4 = *(const float4*)(w + c);
        float4 q4 = *(const float4*)(query + c);
        s += q4.x * w4.x + q4.y * w4.y + q4.z * w4.z + q4.w * w4.w;
    }
    QH[gid] = s + Bin[(long)v * 2304 + d];
}

// ---------------------------------------------------------------------------
// Learnable-query cross attention (f32). KVH [V,B,N,1536]: k then v.
// ---------------------------------------------------------------------------
__launch_bounds__(256, 2)
__global__ void cross_attn(const float* __restrict__ KVH, const float* __restrict__ QH,
                           float* __restrict__ C2)
{
    const int h = blockIdx.x, b = blockIdx.y, v = blockIdx.z;
    const int t = threadIdx.x;
    __shared__ float qv[64];
    __shared__ float p[256];
    __shared__ float part[4][64];
    __shared__ float wred[4], wred2[4];

    if (t < 64) qv[t] = QH[(v * 12 + h) * 64 + t];
    __syncthreads();

    const float* krow = KVH + ((long)((v * 4 + b) * 256 + t)) * 1536 + h * 64;
    float s = 0.f;
    #pragma unroll
    for (int e = 0; e < 64; e += 4) {
        float4 k4 = *(const float4*)(krow + e);
        s += qv[e] * k4.x + qv[e + 1] * k4.y + qv[e + 2] * k4.z + qv[e + 3] * k4.w;
    }
    s *= 0.125f;
    float m4 = s;
    #pragma unroll
    for (int off = 32; off > 0; off >>= 1) m4 = fmaxf(m4, __shfl_down(m4, off));
    if ((t & 63) == 0) wred[t >> 6] = m4;
    __syncthreads();
    float rmax = fmaxf(fmaxf(wred[0], wred[1]), fmaxf(wred[2], wred[3]));
    float ev = __expf(s - rmax);
    p[t] = ev;
    float s4 = ev;
    #pragma unroll
    for (int off = 32; off > 0; off >>= 1) s4 += __shfl_down(s4, off);
    if ((t & 63) == 0) wred2[t >> 6] = s4;
    __syncthreads();
    float inv = 1.0f / (wred2[0] + wred2[1] + wred2[2] + wred2[3]);

    const int e = t & 63, ch = t >> 6;
    const float* vbase = KVH + ((long)((v * 4 + b) * 256)) * 1536 + 768 + h * 64 + e;
    float accv = 0.f;
    for (int m = ch * 64; m < ch * 64 + 64; ++m)
        accv += p[m] * vbase[(long)m * 1536];
    part[ch][e] = accv;
    __syncthreads();
    if (t < 64)
        C2[(v * 4 + b) * 768 + h * 64 + t] =
            (part[0][t] + part[1][t] + part[2][t] + part[3][t]) * inv;
}

// ---------------------------------------------------------------------------
// out stage 1: one wave per output row d; 768 blocks x 4 waves.
// ---------------------------------------------------------------------------
__launch_bounds__(256, 4)
__global__ void out_matvec(const float* __restrict__ C2, const float* __restrict__ Wout,
                           const float* __restrict__ Bout, float* __restrict__ obc)
{
    const int bi   = blockIdx.x;
    const int v    = bi / 192;
    const int dblk = bi - v * 192;
    const int t    = threadIdx.x;
    const int wave = t >> 6;
    const int lane = t & 63;
    const int d    = dblk * 4 + wave;

    __shared__ float c2s[3072];
    #pragma unroll
    for (int idx = 0; idx < 3072; idx += 256) c2s[idx + t] = C2[v * 3072 + idx + t];
    __syncthreads();

    const float* w = Wout + ((long)v * 768 + d) * 768;
    float acc0 = 0.f, acc1 = 0.f, acc2 = 0.f, acc3 = 0.f;
    #pragma unroll
    for (int k = 0; k < 3; ++k) {
        int c = k * 256 + lane * 4;
        float4 w4 = *(const float4*)(w + c);
        float4 a0 = *(const float4*)&c2s[c];
        float4 a1 = *(const float4*)&c2s[768 + c];
        float4 a2 = *(const float4*)&c2s[1536 + c];
        float4 a3 = *(const float4*)&c2s[2304 + c];
        acc0 += w4.x * a0.x + w4.y * a0.y + w4.z * a0.z + w4.w * a0.w;
        acc1 += w4.x * a1.x + w4.y * a1.y + w4.z * a1.z + w4.w * a1.w;
        acc2 += w4.x * a2.x + w4.y * a2.y + w4.z * a2.z + w4.w * a2.w;
        acc3 += w4.x * a3.x + w4.y * a3.y + w4.z * a3.z + w4.w * a3.w;
    }
    #pragma unroll
    for (int off = 32; off > 0; off >>= 1) {
        acc0 += __shfl_down(acc0, off);
        acc1 += __shfl_down(acc1, off);
        acc2 += __shfl_down(acc2, off);
        acc3 += __shfl_down(acc3, off);
    }
    if (lane == 0) {
        float bb = Bout[v * 768 + d];
        obc[0 * 3072 + v * 768 + d] = acc0 + bb;
        obc[1 * 3072 + v * 768 + d] = acc1 + bb;
        obc[2 * 3072 + v * 768 + d] = acc2 + bb;
        obc[3 * 3072 + v * 768 + d] = acc3 + bb;
    }
}

// ---------------------------------------------------------------------------
// out stage 2: broadcast over N
// ---------------------------------------------------------------------------
__launch_bounds__(256, 4)
__global__ void out_bcast(const float* __restrict__ obc, float* __restrict__ out)
{
    const int b  = blockIdx.x >> 6;
    const int n0 = (blockIdx.x & 63) * 4;
    const int t  = threadIdx.x;
    const float4* src = (const float4*)(obc + (long)b * 3072);
    float4 v0 = src[t], v1 = src[t + 256], v2 = src[t + 512];
    float4* dst = (float4*)(out + ((long)(b * 256 + n0)) * 3072);
    #pragma unroll
    for (int r = 0; r < 4; ++r) {
        dst[r * 768 + t]       = v0;
        dst[r * 768 + t + 256] = v1;
        dst[r * 768 + t + 512] = v2;
    }
}

// ---------------------------------------------------------------------------
extern "C" void kernel_launch(void* const* d_in, const int* in_sizes, int n_in,
                              void* d_out, int out_size, void* d_ws, size_t ws_size,
                              hipStream_t stream)
{
    const float* X        = (const float*)d_in[0];
    const float* n1g      = (const float*)d_in[1];
    const float* n1b      = (const float*)d_in[2];
    const float* qkv_w    = (const float*)d_in[3];
    const float* proj_w   = (const float*)d_in[4];
    const float* proj_b   = (const float*)d_in[5];
    const float* n2g      = (const float*)d_in[6];
    const float* n2b      = (const float*)d_in[7];
    const float* fc1_w    = (const float*)d_in[8];
    const float* fc1_b    = (const float*)d_in[9];
    const float* fc2_w    = (const float*)d_in[10];
    const float* fc2_b    = (const float*)d_in[11];
    const float* query    = (const float*)d_in[12];
    const float* mha_in_w = (const float*)d_in[13];
    const float* mha_in_b = (const float*)d_in[14];
    const float* mha_out_w= (const float*)d_in[15];
    const float* mha_out_b= (const float*)d_in[16];
    float* out = (float*)d_out;

    char* wsb = (char*)d_ws;
    unsigned short* wbuf = (unsigned short*)wsb;                    // 18,874,368 B
    unsigned short* rgA  = (unsigned short*)(wsb + 18874368);       //  6,291,456 B (Xn -> ctx -> h -> x2)
    char*           rgB  = wsb + 25165824;                          // 25,165,824 B (QKV -> h1 -> KVH)
    float*          xbuf = (float*)(wsb + 50331648);                // 12,582,912 B (x residual, f32)
    float*          qh   = (float*)(wsb + 62914560);
    float*          c2   = (float*)(wsb + 62926848);
    float*          obc  = (float*)(wsb + 62976000);                // 49,152 B

    unsigned short* QKV = (unsigned short*)rgB;
    unsigned short* H1  = (unsigned short*)rgB;
    float*          KVH = (float*)rgB;

    // 1. qkv weights -> bf16, LN1 -> Xn bf16
    conv_bf16<<<3456, 256, 0, stream>>>(qkv_w, wbuf, 7077888);
    ln1_kernel<<<4096, 256, 0, stream>>>(X, n1g, n1b, rgA);
    // 2. QKV = Xn @ qkv_w^T  [V,1024,2304] bf16
    gemm_bf16<0, 1, unsigned short><<<dim3(18, 8, 4), 256, 0, stream>>>(
        rgA, wbuf, nullptr, QKV, 1024, 2304, 768, 2304L * 768, 0, 0, 0);
    // 3. fusion attention -> ctx_mean bf16 [V,1024,768]
    fusion_attn_mfma<<<dim3(4, 48, 4), 256, 0, stream>>>(QKV, rgA);
    // 4. x = 2*(ctx @ proj_w^T) + 2*proj_b  f32, split-K x2 atomic
    conv_bf16<<<1152, 256, 0, stream>>>(proj_w, wbuf, 2359296);
    init2b<<<3072, 256, 0, stream>>>(proj_b, xbuf);
    gemm_bf16<5, 2, float><<<dim3(6, 8, 8), 256, 0, stream>>>(
        rgA, wbuf, nullptr, xbuf, 1024, 768, 768, 768L * 768, 0, 0, 0);
    // 5. h = LN2(x) bf16
    ln2_kernel<<<4096, 256, 0, stream>>>(xbuf, n2g, n2b, rgA);
    // 6. h1 = gelu(h @ fc1_w^T + fc1_b) bf16 [V,1024,3072]
    conv_bf16<<<4608, 256, 0, stream>>>(fc1_w, wbuf, 9437184);
    gemm_bf16<2, 1, unsigned short><<<dim3(24, 8, 4), 256, 0, stream>>>(
        rgA, wbuf, fc1_b, H1, 1024, 3072, 768, 3072L * 768, 0, 3072, 0);
    // 7. xbuf += h1 @ fc2_w^T  (split-K x4 atomic onto residual)
    conv_bf16<<<4608, 256, 0, stream>>>(fc2_w, wbuf, 9437184);
    gemm_bf16<6, 4, float><<<dim3(6, 8, 16), 256, 0, stream>>>(
        H1, wbuf, nullptr, xbuf, 1024, 768, 3072, 768L * 3072, 0, 0, 0);
    //    x2 = xbuf + fc2_b -> bf16 rgA
    conv_bias_bf16<<<1536, 256, 0, stream>>>(xbuf, fc2_b, rgA);
    // 8. KVH = x2 @ [wk;wv]^T + [bk;bv]  f32, split-K x2 atomic (init = bias)
    conv_bf16<<<3456, 256, 0, stream>>>(mha_in_w, wbuf, 7077888);
    init_kvh<<<6144, 256, 0, stream>>>(mha_in_b, KVH);
    gemm_bf16<6, 2, float><<<dim3(12, 8, 8), 256, 0, stream>>>(
        rgA, wbuf, nullptr, KVH, 1024, 1536, 768, 2304L * 768, 768L * 768, 0, 0);
    // 9. small tail
    qh_kernel<<<12, 256, 0, stream>>>(query, mha_in_w, mha_in_b, qh);
    cross_attn<<<dim3(12, 4, 4), 256, 0, stream>>>(KVH, qh, c2);
    out_matvec<<<768, 256, 0, stream>>>(c2, mha_out_w, mha_out_b, obc);
    out_bcast<<<256, 256, 0, stream>>>(obc, out);
}

// Round 6
// 480.218 us; speedup vs baseline: 1.1469x; 1.1469x over previous
//
#include <hip/hip_runtime.h>
#include <math.h>

#define NVIEW 4
#define BATCH 4
#define NSEQ  256
#define CDIM  768
#define HEADS 12
#define HD    64

typedef __attribute__((ext_vector_type(8))) short   short8;
typedef __attribute__((ext_vector_type(8))) unsigned short ushort8;
typedef __attribute__((ext_vector_type(4))) float   float4v;

typedef const __attribute__((address_space(1))) void gas_t;
typedef       __attribute__((address_space(3))) void las_t;

__device__ __forceinline__ unsigned short f2b(float x)
{
    union { float f; unsigned u; } c; c.f = x;
    unsigned r = (c.u + 0x7FFFu + ((c.u >> 16) & 1u)) >> 16;
    return (unsigned short)r;
}

// ---------------------------------------------------------------------------
// f32 -> bf16 conversion (n must be multiple of 8)
// ---------------------------------------------------------------------------
__global__ void conv_bf16(const float* __restrict__ src, unsigned short* __restrict__ dst, int n)
{
    int idx = (blockIdx.x * 256 + threadIdx.x) * 8;
    if (idx >= n) return;
    float4 a = *(const float4*)(src + idx);
    float4 b = *(const float4*)(src + idx + 4);
    ushort8 o;
    o[0] = f2b(a.x); o[1] = f2b(a.y); o[2] = f2b(a.z); o[3] = f2b(a.w);
    o[4] = f2b(b.x); o[5] = f2b(b.y); o[6] = f2b(b.z); o[7] = f2b(b.w);
    *(ushort8*)(dst + idx) = o;
}

// ---------------------------------------------------------------------------
// LayerNorm -> bf16 out
// ---------------------------------------------------------------------------
__device__ __forceinline__ void block_ln_row_b(const float* __restrict__ xrow,
                                               const float* __restrict__ g,
                                               const float* __restrict__ b,
                                               unsigned short* __restrict__ orow)
{
    const int t = threadIdx.x;
    float x0 = xrow[t], x1 = xrow[t + 256], x2 = xrow[t + 512];
    float s  = x0 + x1 + x2;
    float s2 = x0 * x0 + x1 * x1 + x2 * x2;
    #pragma unroll
    for (int off = 32; off > 0; off >>= 1) {
        s  += __shfl_down(s, off);
        s2 += __shfl_down(s2, off);
    }
    __shared__ float w1[4], w2[4];
    if ((t & 63) == 0) { w1[t >> 6] = s; w2[t >> 6] = s2; }
    __syncthreads();
    float S  = w1[0] + w1[1] + w1[2] + w1[3];
    float S2 = w2[0] + w2[1] + w2[2] + w2[3];
    float mean = S * (1.0f / 768.0f);
    float var  = S2 * (1.0f / 768.0f) - mean * mean;
    float inv  = rsqrtf(var + 1e-6f);
    orow[t]       = f2b((x0 - mean) * inv * g[t]       + b[t]);
    orow[t + 256] = f2b((x1 - mean) * inv * g[t + 256] + b[t + 256]);
    orow[t + 512] = f2b((x2 - mean) * inv * g[t + 512] + b[t + 512]);
}

// X:[B,V,N,C] -> Xn bf16 [V,B,N,C]
__global__ void ln1_kernel(const float* __restrict__ X, const float* __restrict__ g,
                           const float* __restrict__ b, unsigned short* __restrict__ Xn)
{
    int rid = blockIdx.x;
    int n  = rid & 255;
    int bv = rid >> 8;
    int bb = bv >> 2, v = bv & 3;
    const float* xrow = X + (long)rid * CDIM;
    unsigned short* orow = Xn + ((long)(v * 4 + bb) * 256 + n) * CDIM;
    block_ln_row_b(xrow, g, b, orow);
}

// f32 in [V,B,N,C] -> bf16 out, per-view gamma/beta
__global__ void ln2_kernel(const float* __restrict__ Xin, const float* __restrict__ g,
                           const float* __restrict__ b, unsigned short* __restrict__ Out)
{
    int rid = blockIdx.x;
    int v = rid >> 10;
    const float* xrow = Xin + (long)rid * CDIM;
    block_ln_row_b(xrow, g + v * CDIM, b + v * CDIM, Out + (long)rid * CDIM);
}

// ---------------------------------------------------------------------------
// bf16 MFMA grouped GEMM: out[v] = A[v](M,K) * W[v]^T(N,K) + epilogue
// TM x 128 tile (TM=128: waves 2x2, 4x4 acc; TM=64: waves 1x4, 4x2 acc), BK=32.
// EPI: 0=store bf16  1=+bias f32  2=+bias,gelu bf16  3=+bias,+resid(f32) bf16
//      4=(+bias)*2 f32
// ---------------------------------------------------------------------------
template <int EPI, int TM, typename OT>
__launch_bounds__(256, 2)
__global__ void gemm_bf16(const unsigned short* __restrict__ A,
                          const unsigned short* __restrict__ W,
                          const float* __restrict__ bias, const float* __restrict__ resid,
                          OT* __restrict__ out, int M, int N, int K,
                          long wStride, long wOff, int bStride, int bOff)
{
    const int v = blockIdx.z;
    const unsigned short* Av = A + (long)v * M * K;
    const unsigned short* Wv = W + v * wStride + wOff;

    __shared__ unsigned short As[TM * 32];
    __shared__ unsigned short Bs[128 * 32];

    const int tid  = threadIdx.x;
    const int lane = tid & 63;
    const int wave = tid >> 6;
    const int l15  = lane & 15;
    const int quad = lane >> 4;
    const int row0 = blockIdx.y * TM, col0 = blockIdx.x * 128;

    constexpr int MI = (TM == 128) ? 4 : 4;   // m-frags per wave
    constexpr int NI = (TM == 128) ? 4 : 2;   // n-frags per wave
    const int mw = (TM == 128) ? (wave & 1) * 64 : 0;
    const int nw = (TM == 128) ? (wave >> 1) * 64 : wave * 32;

    float4v acc[MI][NI];
    #pragma unroll
    for (int i = 0; i < MI; ++i)
        #pragma unroll
        for (int j = 0; j < NI; ++j)
            acc[i][j] = (float4v){0.f, 0.f, 0.f, 0.f};

    const int rB = wave * 32 + (lane >> 2);   // B-tile row for chunk g (g=1: +16)
    const int rA = (TM == 128) ? rB : (wave * 16 + (lane >> 2));
    const int pA = lane & 3;                  // physical 16B slot within row

    for (int k0 = 0; k0 < K; k0 += 32) {
        __syncthreads();
        if constexpr (TM == 128) {
            #pragma unroll
            for (int g = 0; g < 2; ++g) {
                int r = rA + g * 16;
                int c = (pA - ((r >> 1) & 3)) & 3;
                const unsigned short* sa = Av + (long)(row0 + r) * K + k0 + c * 8;
                __builtin_amdgcn_global_load_lds((gas_t*)sa, (las_t*)&As[(wave * 32 + g * 16) * 32], 16, 0, 0);
            }
        } else {
            int r = rA;
            int c = (pA - ((r >> 1) & 3)) & 3;
            const unsigned short* sa = Av + (long)(row0 + r) * K + k0 + c * 8;
            __builtin_amdgcn_global_load_lds((gas_t*)sa, (las_t*)&As[(wave * 16) * 32], 16, 0, 0);
        }
        #pragma unroll
        for (int g = 0; g < 2; ++g) {
            int r = rB + g * 16;
            int c = (pA - ((r >> 1) & 3)) & 3;
            const unsigned short* sw = Wv + (long)(col0 + r) * K + k0 + c * 8;
            __builtin_amdgcn_global_load_lds((gas_t*)sw, (las_t*)&Bs[(wave * 32 + g * 16) * 32], 16, 0, 0);
        }
        __syncthreads();

        short8 af[MI], bfr[NI];
        #pragma unroll
        for (int mi = 0; mi < MI; ++mi) {
            int m = mw + mi * 16 + l15;
            int p = (quad + ((m >> 1) & 3)) & 3;
            af[mi] = *(const short8*)&As[m * 32 + p * 8];
        }
        #pragma unroll
        for (int ni = 0; ni < NI; ++ni) {
            int n = nw + ni * 16 + l15;
            int p = (quad + ((n >> 1) & 3)) & 3;
            bfr[ni] = *(const short8*)&Bs[n * 32 + p * 8];
        }
        #pragma unroll
        for (int mi = 0; mi < MI; ++mi)
            #pragma unroll
            for (int ni = 0; ni < NI; ++ni)
                acc[mi][ni] = __builtin_amdgcn_mfma_f32_16x16x32_bf16(af[mi], bfr[ni], acc[mi][ni], 0, 0, 0);
    }

    #pragma unroll
    for (int mi = 0; mi < MI; ++mi) {
        #pragma unroll
        for (int ni = 0; ni < NI; ++ni) {
            int rowb = row0 + mw + mi * 16 + quad * 4;
            int col  = col0 + nw + ni * 16 + l15;
            float bval = 0.f;
            if (EPI >= 1) bval = bias[v * bStride + bOff + col];
            #pragma unroll
            for (int r = 0; r < 4; ++r) {
                float x = acc[mi][ni][r] + bval;
                long off = (long)v * M * N + (long)(rowb + r) * N + col;
                if constexpr (EPI == 2) {
                    x = 0.5f * x * (1.0f + erff(x * 0.70710678118654752f));
                } else if constexpr (EPI == 3) {
                    x += resid[off];
                } else if constexpr (EPI == 4) {
                    x *= 2.0f;
                }
                if constexpr (sizeof(OT) == 2) ((unsigned short*)out)[off] = f2b(x);
                else                           ((float*)out)[off] = x;
            }
        }
    }
}

// ---------------------------------------------------------------------------
// Fused MFMA fusion-attention.
// grid (qt=4, b*h=48, i=4); block 256 = 4 waves; each wave owns 16 query rows.
// ---------------------------------------------------------------------------
__launch_bounds__(256, 2)
__global__ void fusion_attn_mfma(const unsigned short* __restrict__ QKV,
                                 unsigned short* __restrict__ ctx)
{
    const int qt = blockIdx.x;
    const int b  = blockIdx.y / HEADS;
    const int h  = blockIdx.y % HEADS;
    const int i  = blockIdx.z;
    const int tid  = threadIdx.x;
    const int lane = tid & 63;
    const int wave = tid >> 6;
    const int l15  = lane & 15;
    const int quad = lane >> 4;

    __shared__ unsigned short Qs[64 * 72];
    __shared__ unsigned short Ks[128 * 64];
    __shared__ unsigned short Ps[64 * 136];
    __shared__ unsigned short Vt[64 * 136];

    {
        int r = tid >> 2, p16 = (tid & 3) * 16;
        const unsigned short* src = QKV + ((long)((i * 4 + b) * 256 + qt * 64 + r)) * 2304 + h * 64 + p16;
        *(ushort8*)(&Qs[r * 72 + p16])     = *(const ushort8*)(src);
        *(ushort8*)(&Qs[r * 72 + p16 + 8]) = *(const ushort8*)(src + 8);
    }

    float4v acc_o[4];
    #pragma unroll
    for (int e = 0; e < 4; ++e) acc_o[e] = (float4v){0.f, 0.f, 0.f, 0.f};

    for (int j = 0; j < 4; ++j) {
        const unsigned short* Kb = QKV + ((long)((j * 4 + b) * 256)) * 2304 + 768 + h * 64;
        const unsigned short* Vb = Kb + 768;

        float4v sacc[16];
        #pragma unroll
        for (int t = 0; t < 16; ++t) sacc[t] = (float4v){0.f, 0.f, 0.f, 0.f};

        for (int half = 0; half < 2; ++half) {
            __syncthreads();
            #pragma unroll
            for (int g = 0; g < 4; ++g) {
                int R = wave * 32 + g * 8;
                int r = R + (lane >> 3);
                int p = lane & 7;
                int c = (p - (r & 7)) & 7;
                const unsigned short* src = Kb + (long)(half * 128 + r) * 2304 + c * 8;
                __builtin_amdgcn_global_load_lds((gas_t*)src, (las_t*)&Ks[R * 64], 16, 0, 0);
            }
            __syncthreads();
            #pragma unroll
            for (int ks = 0; ks < 2; ++ks) {
                int lcq = ks * 4 + quad;
                short8 qf = *(const short8*)&Qs[(wave * 16 + l15) * 72 + lcq * 8];
                #pragma unroll
                for (int nn = 0; nn < 8; ++nn) {
                    int n = nn * 16 + l15;
                    int p = (lcq + (n & 7)) & 7;
                    short8 kf = *(const short8*)&Ks[n * 64 + p * 8];
                    sacc[half * 8 + nn] =
                        __builtin_amdgcn_mfma_f32_16x16x32_bf16(qf, kf, sacc[half * 8 + nn], 0, 0, 0);
                }
            }
        }

        float rmax[4] = {-1e30f, -1e30f, -1e30f, -1e30f};
        #pragma unroll
        for (int t = 0; t < 16; ++t)
            #pragma unroll
            for (int r = 0; r < 4; ++r)
                rmax[r] = fmaxf(rmax[r], sacc[t][r] * 0.125f);
        #pragma unroll
        for (int off = 1; off < 16; off <<= 1)
            #pragma unroll
            for (int r = 0; r < 4; ++r)
                rmax[r] = fmaxf(rmax[r], __shfl_xor(rmax[r], off));
        float rsum[4] = {0.f, 0.f, 0.f, 0.f};
        #pragma unroll
        for (int t = 0; t < 16; ++t)
            #pragma unroll
            for (int r = 0; r < 4; ++r) {
                float e = __expf(sacc[t][r] * 0.125f - rmax[r]);
                sacc[t][r] = e;
                rsum[r] += e;
            }
        #pragma unroll
        for (int off = 1; off < 16; off <<= 1)
            #pragma unroll
            for (int r = 0; r < 4; ++r)
                rsum[r] += __shfl_xor(rsum[r], off);
        float invl[4];
        #pragma unroll
        for (int r = 0; r < 4; ++r) invl[r] = 1.0f / rsum[r];

        float4v pv[4];
        #pragma unroll
        for (int e = 0; e < 4; ++e) pv[e] = (float4v){0.f, 0.f, 0.f, 0.f};

        for (int half = 0; half < 2; ++half) {
            __syncthreads();
            #pragma unroll
            for (int nn = 0; nn < 8; ++nn)
                #pragma unroll
                for (int r = 0; r < 4; ++r)
                    Ps[(wave * 16 + quad * 4 + r) * 136 + nn * 16 + l15] = f2b(sacc[half * 8 + nn][r]);
            {
                int n = tid & 127;
                int c0 = (tid >> 7) * 4;
                #pragma unroll
                for (int cc = 0; cc < 4; ++cc) {
                    int c = c0 + cc;
                    ushort8 vv = *(const ushort8*)(Vb + (long)(half * 128 + n) * 2304 + c * 8);
                    #pragma unroll
                    for (int jj = 0; jj < 8; ++jj)
                        Vt[(c * 8 + jj) * 136 + n] = vv[jj];
                }
            }
            __syncthreads();
            #pragma unroll
            for (int ks = 0; ks < 4; ++ks) {
                int lc = ks * 4 + quad;
                short8 pf = *(const short8*)&Ps[(wave * 16 + l15) * 136 + lc * 8];
                #pragma unroll
                for (int et = 0; et < 4; ++et) {
                    short8 vf = *(const short8*)&Vt[(et * 16 + l15) * 136 + lc * 8];
                    pv[et] = __builtin_amdgcn_mfma_f32_16x16x32_bf16(pf, vf, pv[et], 0, 0, 0);
                }
            }
        }
        #pragma unroll
        for (int et = 0; et < 4; ++et)
            #pragma unroll
            for (int r = 0; r < 4; ++r)
                acc_o[et][r] += pv[et][r] * invl[r];
    }

    #pragma unroll
    for (int et = 0; et < 4; ++et)
        #pragma unroll
        for (int r = 0; r < 4; ++r) {
            int row = (i * 4 + b) * 256 + qt * 64 + wave * 16 + quad * 4 + r;
            int col = h * 64 + et * 16 + l15;
            ctx[(long)row * 768 + col] = f2b(acc_o[et][r] * 0.25f);
        }
}

// ---------------------------------------------------------------------------
// qh[v,d] = query . wq[v,d,:] + bq[v,d]
// ---------------------------------------------------------------------------
__global__ void qh_kernel(const float* __restrict__ query, const float* __restrict__ Win,
                          const float* __restrict__ Bin, float* __restrict__ QH)
{
    int gid = blockIdx.x * 256 + threadIdx.x;
    int v = gid / 768, d = gid - v * 768;
    const float* w = Win + ((long)v * 2304 + d) * 768;
    float s = 0.f;
    for (int c = 0; c < 768; c += 4) {
        float4 w4 = *(const float4*)(w + c);
        float4 q4 = *(const float4*)(query + c);
        s += q4.x * w4.x + q4.y * w4.y + q4.z * w4.z + q4.w * w4.w;
    }
    QH[gid] = s + Bin[(long)v * 2304 + d];
}

// ---------------------------------------------------------------------------
// Learnable-query cross attention (f32). KVH [V,B,N,1536]: k then v.
// ---------------------------------------------------------------------------
__launch_bounds__(256, 2)
__global__ void cross_attn(const float* __restrict__ KVH, const float* __restrict__ QH,
                           float* __restrict__ C2)
{
    const int h = blockIdx.x, b = blockIdx.y, v = blockIdx.z;
    const int t = threadIdx.x;
    __shared__ float qv[64];
    __shared__ float p[256];
    __shared__ float part[4][64];
    __shared__ float wred[4], wred2[4];

    if (t < 64) qv[t] = QH[(v * 12 + h) * 64 + t];
    __syncthreads();

    const float* krow = KVH + ((long)((v * 4 + b) * 256 + t)) * 1536 + h * 64;
    float s = 0.f;
    #pragma unroll
    for (int e = 0; e < 64; e += 4) {
        float4 k4 = *(const float4*)(krow + e);
        s += qv[e] * k4.x + qv[e + 1] * k4.y + qv[e + 2] * k4.z + qv[e + 3] * k4.w;
    }
    s *= 0.125f;
    float m4 = s;
    #pragma unroll
    for (int off = 32; off > 0; off >>= 1) m4 = fmaxf(m4, __shfl_down(m4, off));
    if ((t & 63) == 0) wred[t >> 6] = m4;
    __syncthreads();
    float rmax = fmaxf(fmaxf(wred[0], wred[1]), fmaxf(wred[2], wred[3]));
    float ev = __expf(s - rmax);
    p[t] = ev;
    float s4 = ev;
    #pragma unroll
    for (int off = 32; off > 0; off >>= 1) s4 += __shfl_down(s4, off);
    if ((t & 63) == 0) wred2[t >> 6] = s4;
    __syncthreads();
    float inv = 1.0f / (wred2[0] + wred2[1] + wred2[2] + wred2[3]);

    const int e = t & 63, ch = t >> 6;
    const float* vbase = KVH + ((long)((v * 4 + b) * 256)) * 1536 + 768 + h * 64 + e;
    float accv = 0.f;
    for (int m = ch * 64; m < ch * 64 + 64; ++m)
        accv += p[m] * vbase[(long)m * 1536];
    part[ch][e] = accv;
    __syncthreads();
    if (t < 64)
        C2[(v * 4 + b) * 768 + h * 64 + t] =
            (part[0][t] + part[1][t] + part[2][t] + part[3][t]) * inv;
}

// ---------------------------------------------------------------------------
// out stage 1: one wave per output row d; 768 blocks x 4 waves.
// ---------------------------------------------------------------------------
__launch_bounds__(256, 4)
__global__ void out_matvec(const float* __restrict__ C2, const float* __restrict__ Wout,
                           const float* __restrict__ Bout, float* __restrict__ obc)
{
    const int bi   = blockIdx.x;
    const int v    = bi / 192;
    const int dblk = bi - v * 192;
    const int t    = threadIdx.x;
    const int wave = t >> 6;
    const int lane = t & 63;
    const int d    = dblk * 4 + wave;

    __shared__ float c2s[3072];
    #pragma unroll
    for (int idx = 0; idx < 3072; idx += 256) c2s[idx + t] = C2[v * 3072 + idx + t];
    __syncthreads();

    const float* w = Wout + ((long)v * 768 + d) * 768;
    float acc0 = 0.f, acc1 = 0.f, acc2 = 0.f, acc3 = 0.f;
    #pragma unroll
    for (int k = 0; k < 3; ++k) {
        int c = k * 256 + lane * 4;
        float4 w4 = *(const float4*)(w + c);
        float4 a0 = *(const float4*)&c2s[c];
        float4 a1 = *(const float4*)&c2s[768 + c];
        float4 a2 = *(const float4*)&c2s[1536 + c];
        float4 a3 = *(const float4*)&c2s[2304 + c];
        acc0 += w4.x * a0.x + w4.y * a0.y + w4.z * a0.z + w4.w * a0.w;
        acc1 += w4.x * a1.x + w4.y * a1.y + w4.z * a1.z + w4.w * a1.w;
        acc2 += w4.x * a2.x + w4.y * a2.y + w4.z * a2.z + w4.w * a2.w;
        acc3 += w4.x * a3.x + w4.y * a3.y + w4.z * a3.z + w4.w * a3.w;
    }
    #pragma unroll
    for (int off = 32; off > 0; off >>= 1) {
        acc0 += __shfl_down(acc0, off);
        acc1 += __shfl_down(acc1, off);
        acc2 += __shfl_down(acc2, off);
        acc3 += __shfl_down(acc3, off);
    }
    if (lane == 0) {
        float bb = Bout[v * 768 + d];
        obc[0 * 3072 + v * 768 + d] = acc0 + bb;
        obc[1 * 3072 + v * 768 + d] = acc1 + bb;
        obc[2 * 3072 + v * 768 + d] = acc2 + bb;
        obc[3 * 3072 + v * 768 + d] = acc3 + bb;
    }
}

// ---------------------------------------------------------------------------
// out stage 2: broadcast over N
// ---------------------------------------------------------------------------
__launch_bounds__(256, 4)
__global__ void out_bcast(const float* __restrict__ obc, float* __restrict__ out)
{
    const int b  = blockIdx.x >> 6;
    const int n0 = (blockIdx.x & 63) * 4;
    const int t  = threadIdx.x;
    const float4* src = (const float4*)(obc + (long)b * 3072);
    float4 v0 = src[t], v1 = src[t + 256], v2 = src[t + 512];
    float4* dst = (float4*)(out + ((long)(b * 256 + n0)) * 3072);
    #pragma unroll
    for (int r = 0; r < 4; ++r) {
        dst[r * 768 + t]       = v0;
        dst[r * 768 + t + 256] = v1;
        dst[r * 768 + t + 512] = v2;
    }
}

// ---------------------------------------------------------------------------
extern "C" void kernel_launch(void* const* d_in, const int* in_sizes, int n_in,
                              void* d_out, int out_size, void* d_ws, size_t ws_size,
                              hipStream_t stream)
{
    const float* X        = (const float*)d_in[0];
    const float* n1g      = (const float*)d_in[1];
    const float* n1b      = (const float*)d_in[2];
    const float* qkv_w    = (const float*)d_in[3];
    const float* proj_w   = (const float*)d_in[4];
    const float* proj_b   = (const float*)d_in[5];
    const float* n2g      = (const float*)d_in[6];
    const float* n2b      = (const float*)d_in[7];
    const float* fc1_w    = (const float*)d_in[8];
    const float* fc1_b    = (const float*)d_in[9];
    const float* fc2_w    = (const float*)d_in[10];
    const float* fc2_b    = (const float*)d_in[11];
    const float* query    = (const float*)d_in[12];
    const float* mha_in_w = (const float*)d_in[13];
    const float* mha_in_b = (const float*)d_in[14];
    const float* mha_out_w= (const float*)d_in[15];
    const float* mha_out_b= (const float*)d_in[16];
    float* out = (float*)d_out;

    char* wsb = (char*)d_ws;
    unsigned short* wbuf = (unsigned short*)wsb;                    // 18,874,368 B
    unsigned short* rgA  = (unsigned short*)(wsb + 18874368);       //  6,291,456 B (Xn -> ctx -> h -> x2)
    char*           rgB  = wsb + 25165824;                          // 25,165,824 B (QKV -> h1 -> KVH)
    float*          xbuf = (float*)(wsb + 50331648);                // 12,582,912 B (x residual, f32)
    float*          qh   = (float*)(wsb + 62914560);
    float*          c2   = (float*)(wsb + 62926848);
    float*          obc  = (float*)(wsb + 62976000);                // 49,152 B

    unsigned short* QKV = (unsigned short*)rgB;
    unsigned short* H1  = (unsigned short*)rgB;
    float*          KVH = (float*)rgB;

    // 1. qkv weights -> bf16, LN1 -> Xn bf16
    conv_bf16<<<3456, 256, 0, stream>>>(qkv_w, wbuf, 7077888);
    ln1_kernel<<<4096, 256, 0, stream>>>(X, n1g, n1b, rgA);
    // 2. QKV = Xn @ qkv_w^T  [V,1024,2304] bf16   (TM=128; 576 blocks)
    gemm_bf16<0, 128, unsigned short><<<dim3(18, 8, 4), 256, 0, stream>>>(
        rgA, wbuf, nullptr, nullptr, QKV, 1024, 2304, 768, 2304L * 768, 0, 0, 0);
    // 3. fusion attention -> ctx_mean bf16 [V,1024,768]
    fusion_attn_mfma<<<dim3(4, 48, 4), 256, 0, stream>>>(QKV, rgA);
    // 4. x = 2*(ctx @ proj_w^T + proj_b)  f32    (TM=64; 384 blocks)
    conv_bf16<<<1152, 256, 0, stream>>>(proj_w, wbuf, 2359296);
    gemm_bf16<4, 64, float><<<dim3(6, 16, 4), 256, 0, stream>>>(
        rgA, wbuf, proj_b, nullptr, xbuf, 1024, 768, 768, 768L * 768, 0, 768, 0);
    // 5. h = LN2(x) bf16
    ln2_kernel<<<4096, 256, 0, stream>>>(xbuf, n2g, n2b, rgA);
    // 6. h1 = gelu(h @ fc1_w^T + fc1_b) bf16 [V,1024,3072]  (TM=128; 768 blocks)
    conv_bf16<<<4608, 256, 0, stream>>>(fc1_w, wbuf, 9437184);
    gemm_bf16<2, 128, unsigned short><<<dim3(24, 8, 4), 256, 0, stream>>>(
        rgA, wbuf, fc1_b, nullptr, H1, 1024, 3072, 768, 3072L * 768, 0, 3072, 0);
    // 7. x2 = x + (h1 @ fc2_w^T + fc2_b) bf16   (TM=64; 384 blocks)
    conv_bf16<<<4608, 256, 0, stream>>>(fc2_w, wbuf, 9437184);
    gemm_bf16<3, 64, unsigned short><<<dim3(6, 16, 4), 256, 0, stream>>>(
        H1, wbuf, fc2_b, xbuf, rgA, 1024, 768, 3072, 768L * 3072, 0, 768, 0);
    // 8. KVH = x2 @ [wk;wv]^T + [bk;bv]  f32 [V,1024,1536]  (TM=64; 768 blocks)
    conv_bf16<<<3456, 256, 0, stream>>>(mha_in_w, wbuf, 7077888);
    gemm_bf16<1, 64, float><<<dim3(12, 16, 4), 256, 0, stream>>>(
        rgA, wbuf, mha_in_b, nullptr, KVH, 1024, 1536, 768, 2304L * 768, 768L * 768, 2304, 768);
    // 9. small tail
    qh_kernel<<<12, 256, 0, stream>>>(query, mha_in_w, mha_in_b, qh);
    cross_attn<<<dim3(12, 4, 4), 256, 0, stream>>>(KVH, qh, c2);
    out_matvec<<<768, 256, 0, stream>>>(c2, mha_out_w, mha_out_b, obc);
    out_bcast<<<256, 256, 0, stream>>>(obc, out);
}

// Round 7
// 447.136 us; speedup vs baseline: 1.2317x; 1.0740x over previous
//
#include <hip/hip_runtime.h>
#include <math.h>

#define NVIEW 4
#define BATCH 4
#define NSEQ  256
#define CDIM  768
#define HEADS 12
#define HD    64

typedef __attribute__((ext_vector_type(8))) short   short8;
typedef __attribute__((ext_vector_type(8))) unsigned short ushort8;
typedef __attribute__((ext_vector_type(4))) float   float4v;

typedef const __attribute__((address_space(1))) void gas_t;
typedef       __attribute__((address_space(3))) void las_t;

__device__ __forceinline__ unsigned short f2b(float x)
{
    union { float f; unsigned u; } c; c.f = x;
    unsigned r = (c.u + 0x7FFFu + ((c.u >> 16) & 1u)) >> 16;
    return (unsigned short)r;
}

// ---------------------------------------------------------------------------
// f32 -> bf16 conversion (n must be multiple of 8)
// ---------------------------------------------------------------------------
__global__ void conv_bf16(const float* __restrict__ src, unsigned short* __restrict__ dst, int n)
{
    int idx = (blockIdx.x * 256 + threadIdx.x) * 8;
    if (idx >= n) return;
    float4 a = *(const float4*)(src + idx);
    float4 b = *(const float4*)(src + idx + 4);
    ushort8 o;
    o[0] = f2b(a.x); o[1] = f2b(a.y); o[2] = f2b(a.z); o[3] = f2b(a.w);
    o[4] = f2b(b.x); o[5] = f2b(b.y); o[6] = f2b(b.z); o[7] = f2b(b.w);
    *(ushort8*)(dst + idx) = o;
}

// ---------------------------------------------------------------------------
// LayerNorm -> bf16 out
// ---------------------------------------------------------------------------
__device__ __forceinline__ void block_ln_row_b(const float* __restrict__ xrow,
                                               const float* __restrict__ g,
                                               const float* __restrict__ b,
                                               unsigned short* __restrict__ orow)
{
    const int t = threadIdx.x;
    float x0 = xrow[t], x1 = xrow[t + 256], x2 = xrow[t + 512];
    float s  = x0 + x1 + x2;
    float s2 = x0 * x0 + x1 * x1 + x2 * x2;
    #pragma unroll
    for (int off = 32; off > 0; off >>= 1) {
        s  += __shfl_down(s, off);
        s2 += __shfl_down(s2, off);
    }
    __shared__ float w1[4], w2[4];
    if ((t & 63) == 0) { w1[t >> 6] = s; w2[t >> 6] = s2; }
    __syncthreads();
    float S  = w1[0] + w1[1] + w1[2] + w1[3];
    float S2 = w2[0] + w2[1] + w2[2] + w2[3];
    float mean = S * (1.0f / 768.0f);
    float var  = S2 * (1.0f / 768.0f) - mean * mean;
    float inv  = rsqrtf(var + 1e-6f);
    orow[t]       = f2b((x0 - mean) * inv * g[t]       + b[t]);
    orow[t + 256] = f2b((x1 - mean) * inv * g[t + 256] + b[t + 256]);
    orow[t + 512] = f2b((x2 - mean) * inv * g[t + 512] + b[t + 512]);
}

// X:[B,V,N,C] -> Xn bf16 [V,B,N,C]
__global__ void ln1_kernel(const float* __restrict__ X, const float* __restrict__ g,
                           const float* __restrict__ b, unsigned short* __restrict__ Xn)
{
    int rid = blockIdx.x;
    int n  = rid & 255;
    int bv = rid >> 8;
    int bb = bv >> 2, v = bv & 3;
    const float* xrow = X + (long)rid * CDIM;
    unsigned short* orow = Xn + ((long)(v * 4 + bb) * 256 + n) * CDIM;
    block_ln_row_b(xrow, g, b, orow);
}

// f32 in [V,B,N,C] -> bf16 out, per-view gamma/beta
__global__ void ln2_kernel(const float* __restrict__ Xin, const float* __restrict__ g,
                           const float* __restrict__ b, unsigned short* __restrict__ Out)
{
    int rid = blockIdx.x;
    int v = rid >> 10;
    const float* xrow = Xin + (long)rid * CDIM;
    block_ln_row_b(xrow, g + v * CDIM, b + v * CDIM, Out + (long)rid * CDIM);
}

// ---------------------------------------------------------------------------
// bf16 MFMA grouped GEMM: out[v] = A[v](M,K) * W[v]^T(N,K) + epilogue
// TM x 128 tile, BK=64 (2 MFMA k-steps per staging iter).
// TM=128: waves 2x2, 4x4 acc; TM=64: waves 1x4, 4x2 acc.
// Row = 8 chunks of 16B; chunk c stored at physical slot p = c ^ (row&7).
// EPI: 0=store bf16  1=+bias f32  2=+bias,gelu bf16  3=+bias,+resid(f32) bf16
//      4=(+bias)*2 f32
// ---------------------------------------------------------------------------
template <int EPI, int TM, typename OT>
__launch_bounds__(256, 2)
__global__ void gemm_bf16(const unsigned short* __restrict__ A,
                          const unsigned short* __restrict__ W,
                          const float* __restrict__ bias, const float* __restrict__ resid,
                          OT* __restrict__ out, int M, int N, int K,
                          long wStride, long wOff, int bStride, int bOff)
{
    const int v = blockIdx.z;
    const unsigned short* Av = A + (long)v * M * K;
    const unsigned short* Wv = W + v * wStride + wOff;

    __shared__ unsigned short As[TM * 64];
    __shared__ unsigned short Bs[128 * 64];

    const int tid  = threadIdx.x;
    const int lane = tid & 63;
    const int wave = tid >> 6;
    const int l15  = lane & 15;
    const int quad = lane >> 4;
    const int row0 = blockIdx.y * TM, col0 = blockIdx.x * 128;

    constexpr int MI = 4;
    constexpr int NI = (TM == 128) ? 4 : 2;
    const int mw = (TM == 128) ? (wave & 1) * 64 : 0;
    const int nw = (TM == 128) ? (wave >> 1) * 64 : wave * 32;

    float4v acc[MI][NI];
    #pragma unroll
    for (int i = 0; i < MI; ++i)
        #pragma unroll
        for (int j = 0; j < NI; ++j)
            acc[i][j] = (float4v){0.f, 0.f, 0.f, 0.f};

    const int lr8 = lane >> 3;   // 0..7 row-within-group
    const int p8  = lane & 7;    // physical 16B slot

    for (int k0 = 0; k0 < K; k0 += 64) {
        __syncthreads();
        // stage A: groups of 8 rows x 128B; TM/32 groups per wave
        #pragma unroll
        for (int g = 0; g < TM / 32; ++g) {
            int G = wave * (TM / 32) + g;
            int r = G * 8 + lr8;
            int c = p8 ^ (r & 7);
            const unsigned short* sa = Av + (long)(row0 + r) * K + k0 + c * 8;
            __builtin_amdgcn_global_load_lds((gas_t*)sa, (las_t*)&As[G * 512], 16, 0, 0);
        }
        // stage B: 4 groups per wave
        #pragma unroll
        for (int g = 0; g < 4; ++g) {
            int G = wave * 4 + g;
            int r = G * 8 + lr8;
            int c = p8 ^ (r & 7);
            const unsigned short* sw = Wv + (long)(col0 + r) * K + k0 + c * 8;
            __builtin_amdgcn_global_load_lds((gas_t*)sw, (las_t*)&Bs[G * 512], 16, 0, 0);
        }
        __syncthreads();

        #pragma unroll
        for (int ks = 0; ks < 2; ++ks) {
            short8 af[MI], bfr[NI];
            #pragma unroll
            for (int mi = 0; mi < MI; ++mi) {
                int m = mw + mi * 16 + l15;
                int p = (ks * 4 + quad) ^ (m & 7);
                af[mi] = *(const short8*)&As[m * 64 + p * 8];
            }
            #pragma unroll
            for (int ni = 0; ni < NI; ++ni) {
                int n = nw + ni * 16 + l15;
                int p = (ks * 4 + quad) ^ (n & 7);
                bfr[ni] = *(const short8*)&Bs[n * 64 + p * 8];
            }
            #pragma unroll
            for (int mi = 0; mi < MI; ++mi)
                #pragma unroll
                for (int ni = 0; ni < NI; ++ni)
                    acc[mi][ni] = __builtin_amdgcn_mfma_f32_16x16x32_bf16(af[mi], bfr[ni], acc[mi][ni], 0, 0, 0);
        }
    }

    #pragma unroll
    for (int mi = 0; mi < MI; ++mi) {
        #pragma unroll
        for (int ni = 0; ni < NI; ++ni) {
            int rowb = row0 + mw + mi * 16 + quad * 4;
            int col  = col0 + nw + ni * 16 + l15;
            float bval = 0.f;
            if (EPI >= 1) bval = bias[v * bStride + bOff + col];
            #pragma unroll
            for (int r = 0; r < 4; ++r) {
                float x = acc[mi][ni][r] + bval;
                long off = (long)v * M * N + (long)(rowb + r) * N + col;
                if constexpr (EPI == 2) {
                    x = 0.5f * x * (1.0f + erff(x * 0.70710678118654752f));
                } else if constexpr (EPI == 3) {
                    x += resid[off];
                } else if constexpr (EPI == 4) {
                    x *= 2.0f;
                }
                if constexpr (sizeof(OT) == 2) ((unsigned short*)out)[off] = f2b(x);
                else                           ((float*)out)[off] = x;
            }
        }
    }
}

// ---------------------------------------------------------------------------
// Fused MFMA fusion-attention.
// grid (qt=4, b*h=48, i=4); block 256 = 4 waves; each wave owns 16 query rows.
// ---------------------------------------------------------------------------
__launch_bounds__(256, 2)
__global__ void fusion_attn_mfma(const unsigned short* __restrict__ QKV,
                                 unsigned short* __restrict__ ctx)
{
    const int qt = blockIdx.x;
    const int b  = blockIdx.y / HEADS;
    const int h  = blockIdx.y % HEADS;
    const int i  = blockIdx.z;
    const int tid  = threadIdx.x;
    const int lane = tid & 63;
    const int wave = tid >> 6;
    const int l15  = lane & 15;
    const int quad = lane >> 4;

    __shared__ unsigned short Qs[64 * 72];
    __shared__ unsigned short Ks[128 * 64];
    __shared__ unsigned short Ps[64 * 136];
    __shared__ unsigned short Vt[64 * 136];

    {
        int r = tid >> 2, p16 = (tid & 3) * 16;
        const unsigned short* src = QKV + ((long)((i * 4 + b) * 256 + qt * 64 + r)) * 2304 + h * 64 + p16;
        *(ushort8*)(&Qs[r * 72 + p16])     = *(const ushort8*)(src);
        *(ushort8*)(&Qs[r * 72 + p16 + 8]) = *(const ushort8*)(src + 8);
    }

    float4v acc_o[4];
    #pragma unroll
    for (int e = 0; e < 4; ++e) acc_o[e] = (float4v){0.f, 0.f, 0.f, 0.f};

    for (int j = 0; j < 4; ++j) {
        const unsigned short* Kb = QKV + ((long)((j * 4 + b) * 256)) * 2304 + 768 + h * 64;
        const unsigned short* Vb = Kb + 768;

        float4v sacc[16];
        #pragma unroll
        for (int t = 0; t < 16; ++t) sacc[t] = (float4v){0.f, 0.f, 0.f, 0.f};

        for (int half = 0; half < 2; ++half) {
            __syncthreads();
            #pragma unroll
            for (int g = 0; g < 4; ++g) {
                int R = wave * 32 + g * 8;
                int r = R + (lane >> 3);
                int p = lane & 7;
                int c = (p - (r & 7)) & 7;
                const unsigned short* src = Kb + (long)(half * 128 + r) * 2304 + c * 8;
                __builtin_amdgcn_global_load_lds((gas_t*)src, (las_t*)&Ks[R * 64], 16, 0, 0);
            }
            __syncthreads();
            #pragma unroll
            for (int ks = 0; ks < 2; ++ks) {
                int lcq = ks * 4 + quad;
                short8 qf = *(const short8*)&Qs[(wave * 16 + l15) * 72 + lcq * 8];
                #pragma unroll
                for (int nn = 0; nn < 8; ++nn) {
                    int n = nn * 16 + l15;
                    int p = (lcq + (n & 7)) & 7;
                    short8 kf = *(const short8*)&Ks[n * 64 + p * 8];
                    sacc[half * 8 + nn] =
                        __builtin_amdgcn_mfma_f32_16x16x32_bf16(qf, kf, sacc[half * 8 + nn], 0, 0, 0);
                }
            }
        }

        float rmax[4] = {-1e30f, -1e30f, -1e30f, -1e30f};
        #pragma unroll
        for (int t = 0; t < 16; ++t)
            #pragma unroll
            for (int r = 0; r < 4; ++r)
                rmax[r] = fmaxf(rmax[r], sacc[t][r] * 0.125f);
        #pragma unroll
        for (int off = 1; off < 16; off <<= 1)
            #pragma unroll
            for (int r = 0; r < 4; ++r)
                rmax[r] = fmaxf(rmax[r], __shfl_xor(rmax[r], off));
        float rsum[4] = {0.f, 0.f, 0.f, 0.f};
        #pragma unroll
        for (int t = 0; t < 16; ++t)
            #pragma unroll
            for (int r = 0; r < 4; ++r) {
                float e = __expf(sacc[t][r] * 0.125f - rmax[r]);
                sacc[t][r] = e;
                rsum[r] += e;
            }
        #pragma unroll
        for (int off = 1; off < 16; off <<= 1)
            #pragma unroll
            for (int r = 0; r < 4; ++r)
                rsum[r] += __shfl_xor(rsum[r], off);
        float invl[4];
        #pragma unroll
        for (int r = 0; r < 4; ++r) invl[r] = 1.0f / rsum[r];

        float4v pv[4];
        #pragma unroll
        for (int e = 0; e < 4; ++e) pv[e] = (float4v){0.f, 0.f, 0.f, 0.f};

        for (int half = 0; half < 2; ++half) {
            __syncthreads();
            #pragma unroll
            for (int nn = 0; nn < 8; ++nn)
                #pragma unroll
                for (int r = 0; r < 4; ++r)
                    Ps[(wave * 16 + quad * 4 + r) * 136 + nn * 16 + l15] = f2b(sacc[half * 8 + nn][r]);
            {
                int n = tid & 127;
                int c0 = (tid >> 7) * 4;
                #pragma unroll
                for (int cc = 0; cc < 4; ++cc) {
                    int c = c0 + cc;
                    ushort8 vv = *(const ushort8*)(Vb + (long)(half * 128 + n) * 2304 + c * 8);
                    #pragma unroll
                    for (int jj = 0; jj < 8; ++jj)
                        Vt[(c * 8 + jj) * 136 + n] = vv[jj];
                }
            }
            __syncthreads();
            #pragma unroll
            for (int ks = 0; ks < 4; ++ks) {
                int lc = ks * 4 + quad;
                short8 pf = *(const short8*)&Ps[(wave * 16 + l15) * 136 + lc * 8];
                #pragma unroll
                for (int et = 0; et < 4; ++et) {
                    short8 vf = *(const short8*)&Vt[(et * 16 + l15) * 136 + lc * 8];
                    pv[et] = __builtin_amdgcn_mfma_f32_16x16x32_bf16(pf, vf, pv[et], 0, 0, 0);
                }
            }
        }
        #pragma unroll
        for (int et = 0; et < 4; ++et)
            #pragma unroll
            for (int r = 0; r < 4; ++r)
                acc_o[et][r] += pv[et][r] * invl[r];
    }

    #pragma unroll
    for (int et = 0; et < 4; ++et)
        #pragma unroll
        for (int r = 0; r < 4; ++r) {
            int row = (i * 4 + b) * 256 + qt * 64 + wave * 16 + quad * 4 + r;
            int col = h * 64 + et * 16 + l15;
            ctx[(long)row * 768 + col] = f2b(acc_o[et][r] * 0.25f);
        }
}

// ---------------------------------------------------------------------------
// qh: one wave per output row d (768 blocks x 4 waves).
// qh[v,d] = query . wq[v,d,:] + bq[v,d]
// ---------------------------------------------------------------------------
__launch_bounds__(256, 4)
__global__ void qh_kernel(const float* __restrict__ query, const float* __restrict__ Win,
                          const float* __restrict__ Bin, float* __restrict__ QH)
{
    const int bi   = blockIdx.x;            // 0..767
    const int v    = bi / 192;
    const int dblk = bi - v * 192;
    const int t    = threadIdx.x;
    const int wave = t >> 6;
    const int lane = t & 63;
    const int d    = dblk * 4 + wave;

    __shared__ float qs[768];
    for (int idx = t; idx < 768; idx += 256) qs[idx] = query[idx];
    __syncthreads();

    const float* w = Win + ((long)v * 2304 + d) * 768;
    float acc = 0.f;
    #pragma unroll
    for (int k = 0; k < 3; ++k) {
        int c = k * 256 + lane * 4;
        float4 w4 = *(const float4*)(w + c);
        float4 q4 = *(const float4*)&qs[c];
        acc += w4.x * q4.x + w4.y * q4.y + w4.z * q4.z + w4.w * q4.w;
    }
    #pragma unroll
    for (int off = 32; off > 0; off >>= 1) acc += __shfl_down(acc, off);
    if (lane == 0)
        QH[v * 768 + d] = acc + Bin[(long)v * 2304 + d];
}

// ---------------------------------------------------------------------------
// Learnable-query cross attention (f32). KVH [V,B,N,1536]: k then v.
// ---------------------------------------------------------------------------
__launch_bounds__(256, 2)
__global__ void cross_attn(const float* __restrict__ KVH, const float* __restrict__ QH,
                           float* __restrict__ C2)
{
    const int h = blockIdx.x, b = blockIdx.y, v = blockIdx.z;
    const int t = threadIdx.x;
    __shared__ float qv[64];
    __shared__ float p[256];
    __shared__ float part[4][64];
    __shared__ float wred[4], wred2[4];

    if (t < 64) qv[t] = QH[(v * 12 + h) * 64 + t];
    __syncthreads();

    const float* krow = KVH + ((long)((v * 4 + b) * 256 + t)) * 1536 + h * 64;
    float s = 0.f;
    #pragma unroll
    for (int e = 0; e < 64; e += 4) {
        float4 k4 = *(const float4*)(krow + e);
        s += qv[e] * k4.x + qv[e + 1] * k4.y + qv[e + 2] * k4.z + qv[e + 3] * k4.w;
    }
    s *= 0.125f;
    float m4 = s;
    #pragma unroll
    for (int off = 32; off > 0; off >>= 1) m4 = fmaxf(m4, __shfl_down(m4, off));
    if ((t & 63) == 0) wred[t >> 6] = m4;
    __syncthreads();
    float rmax = fmaxf(fmaxf(wred[0], wred[1]), fmaxf(wred[2], wred[3]));
    float ev = __expf(s - rmax);
    p[t] = ev;
    float s4 = ev;
    #pragma unroll
    for (int off = 32; off > 0; off >>= 1) s4 += __shfl_down(s4, off);
    if ((t & 63) == 0) wred2[t >> 6] = s4;
    __syncthreads();
    float inv = 1.0f / (wred2[0] + wred2[1] + wred2[2] + wred2[3]);

    const int e = t & 63, ch = t >> 6;
    const float* vbase = KVH + ((long)((v * 4 + b) * 256)) * 1536 + 768 + h * 64 + e;
    float accv = 0.f;
    for (int m = ch * 64; m < ch * 64 + 64; ++m)
        accv += p[m] * vbase[(long)m * 1536];
    part[ch][e] = accv;
    __syncthreads();
    if (t < 64)
        C2[(v * 4 + b) * 768 + h * 64 + t] =
            (part[0][t] + part[1][t] + part[2][t] + part[3][t]) * inv;
}

// ---------------------------------------------------------------------------
// out stage 1: one wave per output row d; 768 blocks x 4 waves.
// ---------------------------------------------------------------------------
__launch_bounds__(256, 4)
__global__ void out_matvec(const float* __restrict__ C2, const float* __restrict__ Wout,
                           const float* __restrict__ Bout, float* __restrict__ obc)
{
    const int bi   = blockIdx.x;
    const int v    = bi / 192;
    const int dblk = bi - v * 192;
    const int t    = threadIdx.x;
    const int wave = t >> 6;
    const int lane = t & 63;
    const int d    = dblk * 4 + wave;

    __shared__ float c2s[3072];
    #pragma unroll
    for (int idx = 0; idx < 3072; idx += 256) c2s[idx + t] = C2[v * 3072 + idx + t];
    __syncthreads();

    const float* w = Wout + ((long)v * 768 + d) * 768;
    float acc0 = 0.f, acc1 = 0.f, acc2 = 0.f, acc3 = 0.f;
    #pragma unroll
    for (int k = 0; k < 3; ++k) {
        int c = k * 256 + lane * 4;
        float4 w4 = *(const float4*)(w + c);
        float4 a0 = *(const float4*)&c2s[c];
        float4 a1 = *(const float4*)&c2s[768 + c];
        float4 a2 = *(const float4*)&c2s[1536 + c];
        float4 a3 = *(const float4*)&c2s[2304 + c];
        acc0 += w4.x * a0.x + w4.y * a0.y + w4.z * a0.z + w4.w * a0.w;
        acc1 += w4.x * a1.x + w4.y * a1.y + w4.z * a1.z + w4.w * a1.w;
        acc2 += w4.x * a2.x + w4.y * a2.y + w4.z * a2.z + w4.w * a2.w;
        acc3 += w4.x * a3.x + w4.y * a3.y + w4.z * a3.z + w4.w * a3.w;
    }
    #pragma unroll
    for (int off = 32; off > 0; off >>= 1) {
        acc0 += __shfl_down(acc0, off);
        acc1 += __shfl_down(acc1, off);
        acc2 += __shfl_down(acc2, off);
        acc3 += __shfl_down(acc3, off);
    }
    if (lane == 0) {
        float bb = Bout[v * 768 + d];
        obc[0 * 3072 + v * 768 + d] = acc0 + bb;
        obc[1 * 3072 + v * 768 + d] = acc1 + bb;
        obc[2 * 3072 + v * 768 + d] = acc2 + bb;
        obc[3 * 3072 + v * 768 + d] = acc3 + bb;
    }
}

// ---------------------------------------------------------------------------
// out stage 2: broadcast over N
// ---------------------------------------------------------------------------
__launch_bounds__(256, 4)
__global__ void out_bcast(const float* __restrict__ obc, float* __restrict__ out)
{
    const int b  = blockIdx.x >> 6;
    const int n0 = (blockIdx.x & 63) * 4;
    const int t  = threadIdx.x;
    const float4* src = (const float4*)(obc + (long)b * 3072);
    float4 v0 = src[t], v1 = src[t + 256], v2 = src[t + 512];
    float4* dst = (float4*)(out + ((long)(b * 256 + n0)) * 3072);
    #pragma unroll
    for (int r = 0; r < 4; ++r) {
        dst[r * 768 + t]       = v0;
        dst[r * 768 + t + 256] = v1;
        dst[r * 768 + t + 512] = v2;
    }
}

// ---------------------------------------------------------------------------
extern "C" void kernel_launch(void* const* d_in, const int* in_sizes, int n_in,
                              void* d_out, int out_size, void* d_ws, size_t ws_size,
                              hipStream_t stream)
{
    const float* X        = (const float*)d_in[0];
    const float* n1g      = (const float*)d_in[1];
    const float* n1b      = (const float*)d_in[2];
    const float* qkv_w    = (const float*)d_in[3];
    const float* proj_w   = (const float*)d_in[4];
    const float* proj_b   = (const float*)d_in[5];
    const float* n2g      = (const float*)d_in[6];
    const float* n2b      = (const float*)d_in[7];
    const float* fc1_w    = (const float*)d_in[8];
    const float* fc1_b    = (const float*)d_in[9];
    const float* fc2_w    = (const float*)d_in[10];
    const float* fc2_b    = (const float*)d_in[11];
    const float* query    = (const float*)d_in[12];
    const float* mha_in_w = (const float*)d_in[13];
    const float* mha_in_b = (const float*)d_in[14];
    const float* mha_out_w= (const float*)d_in[15];
    const float* mha_out_b= (const float*)d_in[16];
    float* out = (float*)d_out;

    char* wsb = (char*)d_ws;
    unsigned short* wbuf = (unsigned short*)wsb;                    // 18,874,368 B
    unsigned short* rgA  = (unsigned short*)(wsb + 18874368);       //  6,291,456 B (Xn -> ctx -> h -> x2)
    char*           rgB  = wsb + 25165824;                          // 25,165,824 B (QKV -> h1 -> KVH)
    float*          xbuf = (float*)(wsb + 50331648);                // 12,582,912 B (x residual, f32)
    float*          qh   = (float*)(wsb + 62914560);
    float*          c2   = (float*)(wsb + 62926848);
    float*          obc  = (float*)(wsb + 62976000);                // 49,152 B

    unsigned short* QKV = (unsigned short*)rgB;
    unsigned short* H1  = (unsigned short*)rgB;
    float*          KVH = (float*)rgB;

    // 1. qkv weights -> bf16, LN1 -> Xn bf16
    conv_bf16<<<3456, 256, 0, stream>>>(qkv_w, wbuf, 7077888);
    ln1_kernel<<<4096, 256, 0, stream>>>(X, n1g, n1b, rgA);
    // 2. QKV = Xn @ qkv_w^T  [V,1024,2304] bf16   (TM=128; 576 blocks)
    gemm_bf16<0, 128, unsigned short><<<dim3(18, 8, 4), 256, 0, stream>>>(
        rgA, wbuf, nullptr, nullptr, QKV, 1024, 2304, 768, 2304L * 768, 0, 0, 0);
    // 3. fusion attention -> ctx_mean bf16 [V,1024,768]
    fusion_attn_mfma<<<dim3(4, 48, 4), 256, 0, stream>>>(QKV, rgA);
    // 4. x = 2*(ctx @ proj_w^T + proj_b)  f32    (TM=64; 384 blocks)
    conv_bf16<<<1152, 256, 0, stream>>>(proj_w, wbuf, 2359296);
    gemm_bf16<4, 64, float><<<dim3(6, 16, 4), 256, 0, stream>>>(
        rgA, wbuf, proj_b, nullptr, xbuf, 1024, 768, 768, 768L * 768, 0, 768, 0);
    // 5. h = LN2(x) bf16
    ln2_kernel<<<4096, 256, 0, stream>>>(xbuf, n2g, n2b, rgA);
    // 6. h1 = gelu(h @ fc1_w^T + fc1_b) bf16 [V,1024,3072]  (TM=128; 768 blocks)
    conv_bf16<<<4608, 256, 0, stream>>>(fc1_w, wbuf, 9437184);
    gemm_bf16<2, 128, unsigned short><<<dim3(24, 8, 4), 256, 0, stream>>>(
        rgA, wbuf, fc1_b, nullptr, H1, 1024, 3072, 768, 3072L * 768, 0, 3072, 0);
    // 7. x2 = x + (h1 @ fc2_w^T + fc2_b) bf16   (TM=64; 384 blocks)
    conv_bf16<<<4608, 256, 0, stream>>>(fc2_w, wbuf, 9437184);
    gemm_bf16<3, 64, unsigned short><<<dim3(6, 16, 4), 256, 0, stream>>>(
        H1, wbuf, fc2_b, xbuf, rgA, 1024, 768, 3072, 768L * 3072, 0, 768, 0);
    // 8. KVH = x2 @ [wk;wv]^T + [bk;bv]  f32 [V,1024,1536]  (TM=64; 768 blocks)
    conv_bf16<<<3456, 256, 0, stream>>>(mha_in_w, wbuf, 7077888);
    gemm_bf16<1, 64, float><<<dim3(12, 16, 4), 256, 0, stream>>>(
        rgA, wbuf, mha_in_b, nullptr, KVH, 1024, 1536, 768, 2304L * 768, 768L * 768, 2304, 768);
    // 9. small tail
    qh_kernel<<<768, 256, 0, stream>>>(query, mha_in_w, mha_in_b, qh);
    cross_attn<<<dim3(12, 4, 4), 256, 0, stream>>>(KVH, qh, c2);
    out_matvec<<<768, 256, 0, stream>>>(c2, mha_out_w, mha_out_b, obc);
    out_bcast<<<256, 256, 0, stream>>>(obc, out);
}